// Round 3
// baseline (446.196 us; speedup 1.0000x reference)
//
#include <hip/hip_runtime.h>

#define B_ 2
#define S_ 2048
#define D_ 2048
#define H_ 16
#define HD_ 128

typedef _Float16 fp16x2 __attribute__((ext_vector_type(2)));
typedef _Float16 fp16x4 __attribute__((ext_vector_type(4)));
typedef _Float16 fp16x8 __attribute__((ext_vector_type(8)));
typedef float f32x4 __attribute__((ext_vector_type(4)));

__device__ __forceinline__ void gl_lds16(const _Float16* g, _Float16* l) {
  __builtin_amdgcn_global_load_lds((const __attribute__((address_space(1))) void*)g,
                                   (__attribute__((address_space(3))) void*)l, 16, 0, 0);
}

// ---------------- cast x fp32 -> fp16 ----------------
__global__ __launch_bounds__(256) void k_cast(const float* __restrict__ in,
                                              _Float16* __restrict__ out, int n4) {
  int i = blockIdx.x * 256 + threadIdx.x;
  if (i >= n4) return;
  f32x4 v = ((const f32x4*)in)[i];
  fp16x4 h = {(_Float16)v[0], (_Float16)v[1], (_Float16)v[2], (_Float16)v[3]};
  ((fp16x4*)out)[i] = h;
}

// ---------------- transpose+cast 4x W[2048][2048] fp32 -> WT[n][k] fp16 ----------------
__global__ __launch_bounds__(256) void k_trw4(const float* __restrict__ w0,
                                              const float* __restrict__ w1,
                                              const float* __restrict__ w2,
                                              const float* __restrict__ w3,
                                              _Float16* __restrict__ o0,
                                              _Float16* __restrict__ o1,
                                              _Float16* __restrict__ o2,
                                              _Float16* __restrict__ o3) {
  __shared__ float tile[64][65];
  const float* w = (blockIdx.z == 0) ? w0 : (blockIdx.z == 1) ? w1 : (blockIdx.z == 2) ? w2 : w3;
  _Float16* wt = (blockIdx.z == 0) ? o0 : (blockIdx.z == 1) ? o1 : (blockIdx.z == 2) ? o2 : o3;
  int k0 = blockIdx.y * 64, n0 = blockIdx.x * 64;
  int t = threadIdx.x;
  int r = t >> 2, c0 = (t & 3) * 16;
  const float* ip = w + (size_t)(k0 + r) * D_ + n0 + c0;
#pragma unroll
  for (int j = 0; j < 16; j += 4) {
    f32x4 v = *(const f32x4*)(ip + j);
    tile[r][c0 + j] = v[0]; tile[r][c0 + j + 1] = v[1];
    tile[r][c0 + j + 2] = v[2]; tile[r][c0 + j + 3] = v[3];
  }
  __syncthreads();
  _Float16* op = wt + (size_t)(n0 + r) * D_ + k0 + c0;
#pragma unroll
  for (int j = 0; j < 16; j += 8) {
    fp16x8 v;
#pragma unroll
    for (int q = 0; q < 8; ++q) v[q] = (_Float16)tile[c0 + j + q][r];
    *(fp16x8*)(op + j) = v;
  }
}

// ---------------- GEMM (m97 structure): C[M][N] = A16[M][2048] * (BT16[N][2048])^T ----------------
template <typename OUT>
__global__ __launch_bounds__(256) void k_gemm_bt(const _Float16* __restrict__ A,
                                                 const _Float16* __restrict__ BT,
                                                 OUT* __restrict__ C, int N) {
  __shared__ __align__(16) _Float16 lA[128 * 64];
  __shared__ __align__(16) _Float16 lB[128 * 64];
  const int t = threadIdx.x;
  const int m0 = blockIdx.y * 128, n0 = blockIdx.x * 128;
  const int lane = t & 63, w = t >> 6;
  const int l15 = lane & 15, lg = lane >> 4;
  const int wm = (w >> 1) * 64, wn = (w & 1) * 64;
  const int rs = t >> 3, cs = (t & 7) * 8;
  const _Float16* Ag = A + (size_t)(m0 + rs) * 2048 + cs;
  const _Float16* Bg = BT + (size_t)(n0 + rs) * 2048 + cs;
  _Float16* lAw = lA + w * 512;
  _Float16* lBw = lB + w * 512;
  f32x4 acc[4][4] = {};
  for (int k0 = 0; k0 < 2048; k0 += 64) {
#pragma unroll
    for (int i = 0; i < 4; ++i) {
      gl_lds16(Ag + k0 + (size_t)i * 32 * 2048, lAw + i * 2048);
      gl_lds16(Bg + k0 + (size_t)i * 32 * 2048, lBw + i * 2048);
    }
    __syncthreads();
#pragma unroll
    for (int ks = 0; ks < 2; ++ks) {
      const int ko = ks * 32 + 8 * lg;
      fp16x8 af[4], bf[4];
#pragma unroll
      for (int mi = 0; mi < 4; ++mi)
        af[mi] = *(const fp16x8*)&lA[(wm + mi * 16 + l15) * 64 + ko];
#pragma unroll
      for (int ni = 0; ni < 4; ++ni)
        bf[ni] = *(const fp16x8*)&lB[(wn + ni * 16 + l15) * 64 + ko];
#pragma unroll
      for (int mi = 0; mi < 4; ++mi)
#pragma unroll
        for (int ni = 0; ni < 4; ++ni)
          acc[mi][ni] = __builtin_amdgcn_mfma_f32_16x16x32_f16(af[mi], bf[ni], acc[mi][ni], 0, 0, 0);
    }
    __syncthreads();
  }
#pragma unroll
  for (int mi = 0; mi < 4; ++mi)
#pragma unroll
    for (int ni = 0; ni < 4; ++ni) {
      size_t row = m0 + wm + 16 * mi + 4 * lg;
      size_t col = n0 + wn + 16 * ni + l15;
#pragma unroll
      for (int i = 0; i < 4; ++i)
        C[(row + i) * (size_t)N + col] = (OUT)acc[mi][ni][i];
    }
}

// ---------------- RoPE: in fp16 (B,S,H,HD) -> out fp16 (B,H,S,HD) ----------------
__global__ __launch_bounds__(256) void k_rope(const _Float16* __restrict__ in,
                                              const float* __restrict__ cosT,
                                              const float* __restrict__ sinT,
                                              _Float16* __restrict__ out) {
  int idx = blockIdx.x * 256 + threadIdx.x;
  if (idx >= B_ * S_ * H_ * 64) return;
  int dp = idx & 63;
  int hh = (idx >> 6) & (H_ - 1);
  int s = (idx >> 10) & (S_ - 1);
  int b = idx >> 21;
  const _Float16* ip = in + (((size_t)b * S_ + s) * H_ + hh) * HD_ + 2 * dp;
  fp16x2 ab = *(const fp16x2*)ip;
  float a = (float)ab[0], bb = (float)ab[1];
  float c = cosT[s * 64 + dp], sn = sinT[s * 64 + dp];
  fp16x2 o = {(_Float16)(a * c - bb * sn), (_Float16)(a * sn + bb * c)};
  *(fp16x2*)(out + (((size_t)b * H_ + hh) * S_ + s) * HD_ + 2 * dp) = o;
}

// ---------------- V transpose: in fp16 (B,S,H,HD) -> Vt fp16 (B,H,HD,S) ----------------
__global__ __launch_bounds__(256) void k_trv(const _Float16* __restrict__ in,
                                             _Float16* __restrict__ out) {
  __shared__ __align__(16) _Float16 tile[64][72];
  int s0 = blockIdx.x * 64, d0 = blockIdx.y * 64;
  int bh = blockIdx.z;
  int b = bh >> 4, hh = bh & 15;
  int t = threadIdx.x;
  int r = t >> 2, c0 = (t & 3) * 16;
  const _Float16* ip = in + (((size_t)b * S_ + s0 + r) * H_ + hh) * HD_ + d0 + c0;
  *(fp16x8*)&tile[r][c0] = *(const fp16x8*)ip;
  *(fp16x8*)&tile[r][c0 + 8] = *(const fp16x8*)(ip + 8);
  __syncthreads();
  _Float16* op = out + ((size_t)bh * HD_ + d0 + r) * S_ + s0 + c0;
#pragma unroll
  for (int j = 0; j < 16; j += 8) {
    fp16x8 v;
#pragma unroll
    for (int q = 0; q < 8; ++q) v[q] = tile[c0 + j + q][r];
    *(fp16x8*)(op + j) = v;
  }
}

// ---------------- block-sparse flash attention ----------------
// 4-way split-K per qb; 4 k-blocks (64 keys) per inner iteration for ILP +
// amortized softmax. Q,K: (B,H,S,HD) fp16; Vt: (B,H,HD,S) fp16; Oa: (B,S,D) fp16
__global__ __launch_bounds__(256) void k_attn(const _Float16* __restrict__ Q,
                                              const _Float16* __restrict__ K,
                                              const _Float16* __restrict__ Vt,
                                              _Float16* __restrict__ Oa) {
  __shared__ _Float16 o_sh[4][16][132];
  __shared__ float ml_sh[4][2][16];
  const int qb = (S_ / 16 - 1) - blockIdx.x;  // reversed: long blocks first
  const int hh = blockIdx.y, b = blockIdx.z;
  const int t = threadIdx.x;
  const int w = t >> 6, lane = t & 63;
  const int l15 = lane & 15, g4 = (lane >> 4) * 4;
  const size_t bh = (size_t)b * H_ + hh;
  const float scale = 0.08838834764831845f;  // 1/sqrt(128)
  const _Float16* Qp = Q + (bh * S_ + (size_t)qb * 16 + l15) * HD_ + g4;
  fp16x4 qf[8];
#pragma unroll
  for (int d = 0; d < 8; ++d) qf[d] = *(const fp16x4*)(Qp + 16 * d);
  f32x4 o[8] = {};
  float mrun = -3.0e38f, lsum = 0.f;

  // block list for qb: globals {3,7,...,w0-1} (g of them) ++ locals {w0..qb}
  const int w0 = qb & ~3;
  const int g = qb >> 2;
  const int nb = g + (qb - w0) + 1;
  const int ntiles = (nb + 3) >> 2;

  for (int ti = w; ti < ntiles; ti += 4) {
    const int base = 4 * ti;
    f32x4 st[4];
    int kbs[4];
#pragma unroll
    for (int j = 0; j < 4; ++j) {
      const int idx = base + j;
      const bool valid = idx < nb;
      kbs[j] = valid ? (idx < g ? 4 * idx + 3 : w0 + idx - g) : 0;
      const float init = valid ? 0.f : -1.0e30f;  // invalid slots: killed by -1e30 acc
      st[j] = f32x4{init, init, init, init};
    }
    const _Float16* Kp0 = K + (bh * S_ + (size_t)kbs[0] * 16 + l15) * HD_ + g4;
    const _Float16* Kp1 = K + (bh * S_ + (size_t)kbs[1] * 16 + l15) * HD_ + g4;
    const _Float16* Kp2 = K + (bh * S_ + (size_t)kbs[2] * 16 + l15) * HD_ + g4;
    const _Float16* Kp3 = K + (bh * S_ + (size_t)kbs[3] * 16 + l15) * HD_ + g4;
#pragma unroll
    for (int d = 0; d < 8; ++d) {
      fp16x4 k0 = *(const fp16x4*)(Kp0 + 16 * d);
      fp16x4 k1 = *(const fp16x4*)(Kp1 + 16 * d);
      fp16x4 k2 = *(const fp16x4*)(Kp2 + 16 * d);
      fp16x4 k3 = *(const fp16x4*)(Kp3 + 16 * d);
      st[0] = __builtin_amdgcn_mfma_f32_16x16x16f16(k0, qf[d], st[0], 0, 0, 0);
      st[1] = __builtin_amdgcn_mfma_f32_16x16x16f16(k1, qf[d], st[1], 0, 0, 0);
      st[2] = __builtin_amdgcn_mfma_f32_16x16x16f16(k2, qf[d], st[2], 0, 0, 0);
      st[3] = __builtin_amdgcn_mfma_f32_16x16x16f16(k3, qf[d], st[3], 0, 0, 0);
    }
    // one softmax pass over all 64 keys of this tile
    float bm = -3.0e38f;
#pragma unroll
    for (int j = 0; j < 4; ++j)
#pragma unroll
      for (int i = 0; i < 4; ++i) {
        st[j][i] *= scale;
        bm = fmaxf(bm, st[j][i]);
      }
    bm = fmaxf(bm, __shfl_xor(bm, 16));
    bm = fmaxf(bm, __shfl_xor(bm, 32));
    const float mnew = fmaxf(mrun, bm);
    const float corr = __expf(mrun - mnew);
    float p[4][4];
    float ps = 0.f;
#pragma unroll
    for (int j = 0; j < 4; ++j)
#pragma unroll
      for (int i = 0; i < 4; ++i) {
        p[j][i] = __expf(st[j][i] - mnew);
        ps += p[j][i];
      }
    ps += __shfl_xor(ps, 16);
    ps += __shfl_xor(ps, 32);
    lsum = lsum * corr + ps;
    mrun = mnew;
    f32x4 c4;
#pragma unroll
    for (int i = 0; i < 4; ++i) c4[i] = __shfl(corr, g4 + i);
#pragma unroll
    for (int ni = 0; ni < 8; ++ni) {
      o[ni][0] *= c4[0]; o[ni][1] *= c4[1]; o[ni][2] *= c4[2]; o[ni][3] *= c4[3];
    }
    fp16x4 ph[4];
#pragma unroll
    for (int j = 0; j < 4; ++j)
      ph[j] = fp16x4{(_Float16)p[j][0], (_Float16)p[j][1], (_Float16)p[j][2], (_Float16)p[j][3]};
    const _Float16* Vb = Vt + (bh * HD_ + l15) * S_ + g4;
#pragma unroll
    for (int ni = 0; ni < 8; ++ni) {
      const size_t ro = (size_t)16 * ni * S_;
      fp16x4 v0 = *(const fp16x4*)(Vb + ro + kbs[0] * 16);
      fp16x4 v1 = *(const fp16x4*)(Vb + ro + kbs[1] * 16);
      fp16x4 v2 = *(const fp16x4*)(Vb + ro + kbs[2] * 16);
      fp16x4 v3 = *(const fp16x4*)(Vb + ro + kbs[3] * 16);
      o[ni] = __builtin_amdgcn_mfma_f32_16x16x16f16(ph[0], v0, o[ni], 0, 0, 0);
      o[ni] = __builtin_amdgcn_mfma_f32_16x16x16f16(ph[1], v1, o[ni], 0, 0, 0);
      o[ni] = __builtin_amdgcn_mfma_f32_16x16x16f16(ph[2], v2, o[ni], 0, 0, 0);
      o[ni] = __builtin_amdgcn_mfma_f32_16x16x16f16(ph[3], v3, o[ni], 0, 0, 0);
    }
  }

  // stash partials (o in fp16: |err| ~1e-3 relative, merged below in fp32)
  if (lane < 16) { ml_sh[w][0][lane] = mrun; ml_sh[w][1][lane] = lsum; }
#pragma unroll
  for (int ni = 0; ni < 8; ++ni)
#pragma unroll
    for (int i = 0; i < 4; ++i)
      o_sh[w][g4 + i][16 * ni + l15] = (_Float16)o[ni][i];
  __syncthreads();

  // merge 4 partials: thread t -> row r = t>>4, cols cb..cb+7
  const int r = t >> 4, cb = (t & 15) * 8;
  float m0 = ml_sh[0][0][r], m1 = ml_sh[1][0][r], m2 = ml_sh[2][0][r], m3 = ml_sh[3][0][r];
  float M = fmaxf(fmaxf(m0, m1), fmaxf(m2, m3));
  float e0 = __expf(m0 - M), e1 = __expf(m1 - M), e2 = __expf(m2 - M), e3 = __expf(m3 - M);
  float ltot = ml_sh[0][1][r] * e0 + ml_sh[1][1][r] * e1 + ml_sh[2][1][r] * e2 + ml_sh[3][1][r] * e3;
  float inv = 1.f / ltot;
  fp16x8 ov;
#pragma unroll
  for (int j = 0; j < 8; ++j) {
    float v = e0 * (float)o_sh[0][r][cb + j] + e1 * (float)o_sh[1][r][cb + j] +
              e2 * (float)o_sh[2][r][cb + j] + e3 * (float)o_sh[3][r][cb + j];
    ov[j] = (_Float16)(v * inv);
  }
  *(fp16x8*)(Oa + ((size_t)b * S_ + (size_t)qb * 16 + r) * D_ + (size_t)hh * HD_ + cb) = ov;
}

extern "C" void kernel_launch(void* const* d_in, const int* in_sizes, int n_in,
                              void* d_out, int out_size, void* d_ws, size_t ws_size,
                              hipStream_t stream) {
  const float* x = (const float*)d_in[0];
  const float* cosT = (const float*)d_in[1];
  const float* sinT = (const float*)d_in[2];
  const float* wq = (const float*)d_in[3];
  const float* wk = (const float*)d_in[4];
  const float* wv = (const float*)d_in[5];
  const float* wo = (const float*)d_in[6];
  float* out = (float*)d_out;
  char* ws = (char*)d_ws;

  _Float16* x16 = (_Float16*)(ws);                    // 16MB, reused as attn out
  _Float16* wtq = (_Float16*)(ws + (16ull << 20));    // 8MB each
  _Float16* wtk = (_Float16*)(ws + (24ull << 20));
  _Float16* wtv = (_Float16*)(ws + (32ull << 20));
  _Float16* wto = (_Float16*)(ws + (40ull << 20));
  _Float16* Q16 = (_Float16*)(ws + (48ull << 20));    // 16MB
  _Float16* K16 = (_Float16*)(ws + (64ull << 20));    // 16MB
  _Float16* Vt16 = (_Float16*)(ws + (80ull << 20));   // 16MB
  _Float16* tmp16 = (_Float16*)(ws + (96ull << 20));  // 16MB -> 112MB total

  k_cast<<<8192, 256, 0, stream>>>(x, x16, (B_ * S_ * D_) / 4);
  k_trw4<<<dim3(32, 32, 4), 256, 0, stream>>>(wq, wk, wv, wo, wtq, wtk, wtv, wto);

  dim3 gg(D_ / 128, (B_ * S_) / 128);  // (16, 32)
  k_gemm_bt<_Float16><<<gg, 256, 0, stream>>>(x16, wtq, tmp16, D_);
  k_rope<<<16384, 256, 0, stream>>>(tmp16, cosT, sinT, Q16);
  k_gemm_bt<_Float16><<<gg, 256, 0, stream>>>(x16, wtk, tmp16, D_);
  k_rope<<<16384, 256, 0, stream>>>(tmp16, cosT, sinT, K16);
  k_gemm_bt<_Float16><<<gg, 256, 0, stream>>>(x16, wtv, tmp16, D_);
  dim3 gv(S_ / 64, HD_ / 64, B_ * H_);  // (32, 2, 32)
  k_trv<<<gv, 256, 0, stream>>>(tmp16, Vt16);

  _Float16* attn16 = x16;  // x16 no longer needed
  k_attn<<<dim3(S_ / 16, H_, B_), 256, 0, stream>>>(Q16, K16, Vt16, attn16);

  k_gemm_bt<float><<<gg, 256, 0, stream>>>(attn16, wto, out, D_);
}

// Round 4
// 330.030 us; speedup vs baseline: 1.3520x; 1.3520x over previous
//
#include <hip/hip_runtime.h>

#define B_ 2
#define S_ 2048
#define D_ 2048
#define H_ 16
#define HD_ 128

typedef _Float16 fp16x2 __attribute__((ext_vector_type(2)));
typedef _Float16 fp16x4 __attribute__((ext_vector_type(4)));
typedef _Float16 fp16x8 __attribute__((ext_vector_type(8)));
typedef float f32x4 __attribute__((ext_vector_type(4)));

__device__ __forceinline__ void gl_lds16(const _Float16* g, _Float16* l) {
  __builtin_amdgcn_global_load_lds((const __attribute__((address_space(1))) void*)g,
                                   (__attribute__((address_space(3))) void*)l, 16, 0, 0);
}

// ---------------- cast x fp32 -> fp16 ----------------
__global__ __launch_bounds__(256) void k_cast(const float* __restrict__ in,
                                              _Float16* __restrict__ out, int n4) {
  int i = blockIdx.x * 256 + threadIdx.x;
  if (i >= n4) return;
  f32x4 v = ((const f32x4*)in)[i];
  fp16x4 h = {(_Float16)v[0], (_Float16)v[1], (_Float16)v[2], (_Float16)v[3]};
  ((fp16x4*)out)[i] = h;
}

// ---------------- transpose+cast 4x W[2048][2048] fp32 -> WT[n][k] fp16 ----------------
__global__ __launch_bounds__(256) void k_trw4(const float* __restrict__ w0,
                                              const float* __restrict__ w1,
                                              const float* __restrict__ w2,
                                              const float* __restrict__ w3,
                                              _Float16* __restrict__ o0,
                                              _Float16* __restrict__ o1,
                                              _Float16* __restrict__ o2,
                                              _Float16* __restrict__ o3) {
  __shared__ float tile[64][65];
  const float* w = (blockIdx.z == 0) ? w0 : (blockIdx.z == 1) ? w1 : (blockIdx.z == 2) ? w2 : w3;
  _Float16* wt = (blockIdx.z == 0) ? o0 : (blockIdx.z == 1) ? o1 : (blockIdx.z == 2) ? o2 : o3;
  int k0 = blockIdx.y * 64, n0 = blockIdx.x * 64;
  int t = threadIdx.x;
  int r = t >> 2, c0 = (t & 3) * 16;
  const float* ip = w + (size_t)(k0 + r) * D_ + n0 + c0;
#pragma unroll
  for (int j = 0; j < 16; j += 4) {
    f32x4 v = *(const f32x4*)(ip + j);
    tile[r][c0 + j] = v[0]; tile[r][c0 + j + 1] = v[1];
    tile[r][c0 + j + 2] = v[2]; tile[r][c0 + j + 3] = v[3];
  }
  __syncthreads();
  _Float16* op = wt + (size_t)(n0 + r) * D_ + k0 + c0;
#pragma unroll
  for (int j = 0; j < 16; j += 8) {
    fp16x8 v;
#pragma unroll
    for (int q = 0; q < 8; ++q) v[q] = (_Float16)tile[c0 + j + q][r];
    *(fp16x8*)(op + j) = v;
  }
}

// ---------------- GEMM (m97 structure): C[M][N] = A16[M][2048] * (BT16[N][2048])^T ----------------
template <typename OUT>
__global__ __launch_bounds__(256) void k_gemm_bt(const _Float16* __restrict__ A,
                                                 const _Float16* __restrict__ BT,
                                                 OUT* __restrict__ C, int N) {
  __shared__ __align__(16) _Float16 lA[128 * 64];
  __shared__ __align__(16) _Float16 lB[128 * 64];
  const int t = threadIdx.x;
  const int m0 = blockIdx.y * 128, n0 = blockIdx.x * 128;
  const int lane = t & 63, w = t >> 6;
  const int l15 = lane & 15, lg = lane >> 4;
  const int wm = (w >> 1) * 64, wn = (w & 1) * 64;
  const int rs = t >> 3, cs = (t & 7) * 8;
  const _Float16* Ag = A + (size_t)(m0 + rs) * 2048 + cs;
  const _Float16* Bg = BT + (size_t)(n0 + rs) * 2048 + cs;
  _Float16* lAw = lA + w * 512;
  _Float16* lBw = lB + w * 512;
  f32x4 acc[4][4] = {};
  for (int k0 = 0; k0 < 2048; k0 += 64) {
#pragma unroll
    for (int i = 0; i < 4; ++i) {
      gl_lds16(Ag + k0 + (size_t)i * 32 * 2048, lAw + i * 2048);
      gl_lds16(Bg + k0 + (size_t)i * 32 * 2048, lBw + i * 2048);
    }
    __syncthreads();
#pragma unroll
    for (int ks = 0; ks < 2; ++ks) {
      const int ko = ks * 32 + 8 * lg;
      fp16x8 af[4], bf[4];
#pragma unroll
      for (int mi = 0; mi < 4; ++mi)
        af[mi] = *(const fp16x8*)&lA[(wm + mi * 16 + l15) * 64 + ko];
#pragma unroll
      for (int ni = 0; ni < 4; ++ni)
        bf[ni] = *(const fp16x8*)&lB[(wn + ni * 16 + l15) * 64 + ko];
#pragma unroll
      for (int mi = 0; mi < 4; ++mi)
#pragma unroll
        for (int ni = 0; ni < 4; ++ni)
          acc[mi][ni] = __builtin_amdgcn_mfma_f32_16x16x32_f16(af[mi], bf[ni], acc[mi][ni], 0, 0, 0);
    }
    __syncthreads();
  }
#pragma unroll
  for (int mi = 0; mi < 4; ++mi)
#pragma unroll
    for (int ni = 0; ni < 4; ++ni) {
      size_t row = m0 + wm + 16 * mi + 4 * lg;
      size_t col = n0 + wn + 16 * ni + l15;
#pragma unroll
      for (int i = 0; i < 4; ++i)
        C[(row + i) * (size_t)N + col] = (OUT)acc[mi][ni][i];
    }
}

// ---------------- RoPE: in fp16 (B,S,H,HD) -> out fp16 (B,H,S,HD) ----------------
__global__ __launch_bounds__(256) void k_rope(const _Float16* __restrict__ in,
                                              const float* __restrict__ cosT,
                                              const float* __restrict__ sinT,
                                              _Float16* __restrict__ out) {
  int idx = blockIdx.x * 256 + threadIdx.x;
  if (idx >= B_ * S_ * H_ * 64) return;
  int dp = idx & 63;
  int hh = (idx >> 6) & (H_ - 1);
  int s = (idx >> 10) & (S_ - 1);
  int b = idx >> 21;
  const _Float16* ip = in + (((size_t)b * S_ + s) * H_ + hh) * HD_ + 2 * dp;
  fp16x2 ab = *(const fp16x2*)ip;
  float a = (float)ab[0], bb = (float)ab[1];
  float c = cosT[s * 64 + dp], sn = sinT[s * 64 + dp];
  fp16x2 o = {(_Float16)(a * c - bb * sn), (_Float16)(a * sn + bb * c)};
  *(fp16x2*)(out + (((size_t)b * H_ + hh) * S_ + s) * HD_ + 2 * dp) = o;
}

// ---------------- V -> blocked layout: Vb[b][h][kb][128 d][16 k] (4KB contiguous/block) ----------------
__global__ __launch_bounds__(256) void k_trvb(const _Float16* __restrict__ in,
                                              _Float16* __restrict__ out) {
  __shared__ _Float16 tile[16][136];
  const int kb = blockIdx.x, hh = blockIdx.y, b = blockIdx.z;
  const int t = threadIdx.x;
  const int kk = t >> 4, c8 = (t & 15) * 8;
  const _Float16* ip = in + (((size_t)b * S_ + kb * 16 + kk) * H_ + hh) * HD_ + c8;
  *(fp16x8*)&tile[kk][c8] = *(const fp16x8*)ip;
  __syncthreads();
  const int d = t >> 1, k8 = (t & 1) * 8;
  fp16x8 v;
#pragma unroll
  for (int j = 0; j < 8; ++j) v[j] = tile[k8 + j][d];
  *(fp16x8*)(out + ((((size_t)b * H_ + hh) * 128 + kb) * 128 + d) * 16 + k8) = v;
}

// ---------------- block-sparse flash attention, Q-group + LDS-staged K/V ----------------
// One WG per (q-group g, h, b); wave w owns qb=4g+w. Shared k-block list staged
// cooperatively via global_load_lds, double-buffered, counted vmcnt.
// Q,K: (B,H,S,HD) fp16; Vb: blocked (see k_trvb); Oa: (B,S,D) fp16
__global__ __launch_bounds__(256) void k_attn(const _Float16* __restrict__ Q,
                                              const _Float16* __restrict__ K,
                                              const _Float16* __restrict__ Vb,
                                              _Float16* __restrict__ Oa) {
  __shared__ __align__(16) _Float16 sK[2][2][2048];  // [buf][slot][16k x 128d swizzled]
  __shared__ __align__(16) _Float16 sV[2][2][2048];  // [buf][slot][128d x 16k]
  const int qg = 31 - (int)blockIdx.x;  // long groups first
  const int hh = blockIdx.y, b = blockIdx.z;
  const int t = threadIdx.x;
  const int w = t >> 6, lane = t & 63;
  const int l15 = lane & 15, lg = lane >> 4, g4 = lg * 4;
  const int qb = 4 * qg + w;
  const size_t bh = (size_t)b * H_ + hh;
  const float scale = 0.08838834764831845f;  // 1/sqrt(128)

  const _Float16* Qp = Q + (bh * S_ + (size_t)qb * 16 + l15) * HD_ + g4;
  fp16x4 qf[8];
#pragma unroll
  for (int d = 0; d < 8; ++d) qf[d] = *(const fp16x4*)(Qp + 16 * d);
  f32x4 o[8] = {};
  float mrun = -3.0e38f, lsum = 0.f;

  const int L = qg + 4;          // shared list: qg globals {3,7,..} + 4 locals
  const int nch = (L + 1) >> 1;  // chunks of 2 k-blocks

  // staging source coords (K pre-swizzled so LDS-linear dest ^ read-swizzle match)
  const int sr = t >> 4, sc = t & 15;
  const int ksrc_off = sr * 128 + (sc ^ (sr & 7)) * 8;  // halfs
  const _Float16* Kb_g = K + bh * S_ * HD_;
  const _Float16* Vb_g = Vb + bh * (size_t)(128 * 2048);

  auto listkb = [&](int idx) { return idx < qg ? 4 * idx + 3 : 3 * qg + idx; };
  auto stage = [&](int buf, int ci) {
    const int i0 = 2 * ci, i1 = i0 + 1;
    const int kb0 = listkb(i0);
    const int kb1 = (i1 < L) ? listkb(i1) : kb0;
    gl_lds16(Kb_g + (size_t)kb0 * 2048 + ksrc_off, &sK[buf][0][w * 512]);
    gl_lds16(Kb_g + (size_t)kb1 * 2048 + ksrc_off, &sK[buf][1][w * 512]);
    gl_lds16(Vb_g + (size_t)kb0 * 2048 + t * 8, &sV[buf][0][w * 512]);
    gl_lds16(Vb_g + (size_t)kb1 * 2048 + t * 8, &sV[buf][1][w * 512]);
  };

  stage(0, 0);
  const int swz = (l15 & 7) << 4;
  const int krow = l15 * 256;  // bytes

  for (int ci = 0; ci < nch; ++ci) {
    const int cur = ci & 1;
    if (ci + 1 < nch) {
      stage(cur ^ 1, ci + 1);
      asm volatile("s_waitcnt vmcnt(4)" ::: "memory");  // cur chunk arrived, next in flight
    } else {
      asm volatile("s_waitcnt vmcnt(0)" ::: "memory");
    }
    __builtin_amdgcn_s_barrier();

    const int i0 = 2 * ci, i1 = i0 + 1;
    const int kb0 = listkb(i0);
    const bool v0 = kb0 <= qb;
    const bool v1 = (i1 < L) && (listkb(i1) <= qb);
    f32x4 st[2];
    const float in0 = v0 ? 0.f : -1.0e30f, in1 = v1 ? 0.f : -1.0e30f;
    st[0] = f32x4{in0, in0, in0, in0};
    st[1] = f32x4{in1, in1, in1, in1};

    const char* kl = (const char*)&sK[cur][0][0];
#pragma unroll
    for (int dd = 0; dd < 8; ++dd) {
      const int co = (dd * 32 + g4 * 2) ^ swz;
      fp16x4 k0 = *(const fp16x4*)(kl + krow + co);
      fp16x4 k1 = *(const fp16x4*)(kl + 4096 + krow + co);
      st[0] = __builtin_amdgcn_mfma_f32_16x16x16f16(k0, qf[dd], st[0], 0, 0, 0);
      st[1] = __builtin_amdgcn_mfma_f32_16x16x16f16(k1, qf[dd], st[1], 0, 0, 0);
    }
    // softmax over the 32 keys
    float bm = -3.0e38f;
#pragma unroll
    for (int j = 0; j < 2; ++j)
#pragma unroll
      for (int i = 0; i < 4; ++i) {
        st[j][i] *= scale;
        bm = fmaxf(bm, st[j][i]);
      }
    bm = fmaxf(bm, __shfl_xor(bm, 16));
    bm = fmaxf(bm, __shfl_xor(bm, 32));
    const float mnew = fmaxf(mrun, bm);
    const float corr = __expf(mrun - mnew);
    float p[2][4];
    float ps = 0.f;
#pragma unroll
    for (int j = 0; j < 2; ++j)
#pragma unroll
      for (int i = 0; i < 4; ++i) {
        p[j][i] = __expf(st[j][i] - mnew);
        ps += p[j][i];
      }
    ps += __shfl_xor(ps, 16);
    ps += __shfl_xor(ps, 32);
    lsum = lsum * corr + ps;
    mrun = mnew;
    f32x4 c4;
#pragma unroll
    for (int i = 0; i < 4; ++i) c4[i] = __shfl(corr, g4 + i);
#pragma unroll
    for (int ni = 0; ni < 8; ++ni) {
      o[ni][0] *= c4[0]; o[ni][1] *= c4[1]; o[ni][2] *= c4[2]; o[ni][3] *= c4[3];
    }
    fp16x4 ph0 = {(_Float16)p[0][0], (_Float16)p[0][1], (_Float16)p[0][2], (_Float16)p[0][3]};
    fp16x4 ph1 = {(_Float16)p[1][0], (_Float16)p[1][1], (_Float16)p[1][2], (_Float16)p[1][3]};
    const char* vl = (const char*)&sV[cur][0][0];
#pragma unroll
    for (int ni = 0; ni < 8; ++ni) {
      const int vo = (16 * ni + l15) * 32 + g4 * 2;
      fp16x4 vv0 = *(const fp16x4*)(vl + vo);
      fp16x4 vv1 = *(const fp16x4*)(vl + 4096 + vo);
      o[ni] = __builtin_amdgcn_mfma_f32_16x16x16f16(ph0, vv0, o[ni], 0, 0, 0);
      o[ni] = __builtin_amdgcn_mfma_f32_16x16x16f16(ph1, vv1, o[ni], 0, 0, 0);
    }
    __builtin_amdgcn_s_barrier();  // all waves done reading buf before it's re-staged
  }

  const float inv = 1.f / lsum;
  f32x4 li;
#pragma unroll
  for (int i = 0; i < 4; ++i) li[i] = __shfl(inv, g4 + i);
  _Float16* Op = Oa + ((size_t)b * S_ + (size_t)qb * 16 + g4) * D_ + (size_t)hh * HD_ + l15;
#pragma unroll
  for (int ni = 0; ni < 8; ++ni)
#pragma unroll
    for (int i = 0; i < 4; ++i)
      Op[(size_t)i * D_ + 16 * ni] = (_Float16)(o[ni][i] * li[i]);
}

extern "C" void kernel_launch(void* const* d_in, const int* in_sizes, int n_in,
                              void* d_out, int out_size, void* d_ws, size_t ws_size,
                              hipStream_t stream) {
  const float* x = (const float*)d_in[0];
  const float* cosT = (const float*)d_in[1];
  const float* sinT = (const float*)d_in[2];
  const float* wq = (const float*)d_in[3];
  const float* wk = (const float*)d_in[4];
  const float* wv = (const float*)d_in[5];
  const float* wo = (const float*)d_in[6];
  float* out = (float*)d_out;
  char* ws = (char*)d_ws;

  _Float16* x16 = (_Float16*)(ws);                    // 16MB, reused as attn out
  _Float16* wtq = (_Float16*)(ws + (16ull << 20));    // 8MB each
  _Float16* wtk = (_Float16*)(ws + (24ull << 20));
  _Float16* wtv = (_Float16*)(ws + (32ull << 20));
  _Float16* wto = (_Float16*)(ws + (40ull << 20));
  _Float16* Q16 = (_Float16*)(ws + (48ull << 20));    // 16MB
  _Float16* K16 = (_Float16*)(ws + (64ull << 20));    // 16MB
  _Float16* Vb16 = (_Float16*)(ws + (80ull << 20));   // 16MB (blocked V)
  _Float16* tmp16 = (_Float16*)(ws + (96ull << 20));  // 16MB -> 112MB total

  k_cast<<<8192, 256, 0, stream>>>(x, x16, (B_ * S_ * D_) / 4);
  k_trw4<<<dim3(32, 32, 4), 256, 0, stream>>>(wq, wk, wv, wo, wtq, wtk, wtv, wto);

  dim3 gg(D_ / 128, (B_ * S_) / 128);  // (16, 32)
  k_gemm_bt<_Float16><<<gg, 256, 0, stream>>>(x16, wtq, tmp16, D_);
  k_rope<<<16384, 256, 0, stream>>>(tmp16, cosT, sinT, Q16);
  k_gemm_bt<_Float16><<<gg, 256, 0, stream>>>(x16, wtk, tmp16, D_);
  k_rope<<<16384, 256, 0, stream>>>(tmp16, cosT, sinT, K16);
  k_gemm_bt<_Float16><<<gg, 256, 0, stream>>>(x16, wtv, tmp16, D_);
  k_trvb<<<dim3(128, 16, 2), 256, 0, stream>>>(tmp16, Vb16);

  _Float16* attn16 = x16;  // x16 no longer needed
  k_attn<<<dim3(32, H_, B_), 256, 0, stream>>>(Q16, K16, Vb16, attn16);

  k_gemm_bt<float><<<gg, 256, 0, stream>>>(attn16, wto, out, D_);
}

// Round 5
// 298.096 us; speedup vs baseline: 1.4968x; 1.1071x over previous
//
#include <hip/hip_runtime.h>

#define B_ 2
#define S_ 2048
#define D_ 2048
#define H_ 16
#define HD_ 128

typedef _Float16 fp16x2 __attribute__((ext_vector_type(2)));
typedef _Float16 fp16x4 __attribute__((ext_vector_type(4)));
typedef _Float16 fp16x8 __attribute__((ext_vector_type(8)));
typedef float f32x4 __attribute__((ext_vector_type(4)));

__device__ __forceinline__ void gl_lds16(const _Float16* g, _Float16* l) {
  __builtin_amdgcn_global_load_lds((const __attribute__((address_space(1))) void*)g,
                                   (__attribute__((address_space(3))) void*)l, 16, 0, 0);
}

// ---------------- cast x fp32 -> fp16 ----------------
__global__ __launch_bounds__(256) void k_cast(const float* __restrict__ in,
                                              _Float16* __restrict__ out, int n4) {
  int i = blockIdx.x * 256 + threadIdx.x;
  if (i >= n4) return;
  f32x4 v = ((const f32x4*)in)[i];
  fp16x4 h = {(_Float16)v[0], (_Float16)v[1], (_Float16)v[2], (_Float16)v[3]};
  ((fp16x4*)out)[i] = h;
}

// ---------------- transpose+cast 4x W[2048][2048] fp32 -> WT[n][k] fp16 ----------------
__global__ __launch_bounds__(256) void k_trw4(const float* __restrict__ w0,
                                              const float* __restrict__ w1,
                                              const float* __restrict__ w2,
                                              const float* __restrict__ w3,
                                              _Float16* __restrict__ o0,
                                              _Float16* __restrict__ o1,
                                              _Float16* __restrict__ o2,
                                              _Float16* __restrict__ o3) {
  __shared__ float tile[64][65];
  const float* w = (blockIdx.z == 0) ? w0 : (blockIdx.z == 1) ? w1 : (blockIdx.z == 2) ? w2 : w3;
  _Float16* wt = (blockIdx.z == 0) ? o0 : (blockIdx.z == 1) ? o1 : (blockIdx.z == 2) ? o2 : o3;
  int k0 = blockIdx.y * 64, n0 = blockIdx.x * 64;
  int t = threadIdx.x;
  int r = t >> 2, c0 = (t & 3) * 16;
  const float* ip = w + (size_t)(k0 + r) * D_ + n0 + c0;
#pragma unroll
  for (int j = 0; j < 16; j += 4) {
    f32x4 v = *(const f32x4*)(ip + j);
    tile[r][c0 + j] = v[0]; tile[r][c0 + j + 1] = v[1];
    tile[r][c0 + j + 2] = v[2]; tile[r][c0 + j + 3] = v[3];
  }
  __syncthreads();
  _Float16* op = wt + (size_t)(n0 + r) * D_ + k0 + c0;
#pragma unroll
  for (int j = 0; j < 16; j += 8) {
    fp16x8 v;
#pragma unroll
    for (int q = 0; q < 8; ++q) v[q] = (_Float16)tile[c0 + j + q][r];
    *(fp16x8*)(op + j) = v;
  }
}

// ---------------- GEMM (m97 structure + XCD swizzle): C = A16 * BT16^T ----------------
template <typename OUT>
__global__ __launch_bounds__(256) void k_gemm_bt(const _Float16* __restrict__ A,
                                                 const _Float16* __restrict__ BT,
                                                 OUT* __restrict__ C, int N) {
  __shared__ __align__(16) _Float16 lA[128 * 64];
  __shared__ __align__(16) _Float16 lB[128 * 64];
  const int t = threadIdx.x;
  // bijective XCD swizzle over the 512-WG grid (16 n-tiles x 32 m-tiles)
  const int fid = blockIdx.y * 16 + blockIdx.x;
  const int sid = (fid & 7) * 64 + (fid >> 3);
  const int m0 = (sid >> 4) * 128, n0 = (sid & 15) * 128;
  const int lane = t & 63, w = t >> 6;
  const int l15 = lane & 15, lg = lane >> 4;
  const int wm = (w >> 1) * 64, wn = (w & 1) * 64;
  const int rs = t >> 3, cs = (t & 7) * 8;
  const _Float16* Ag = A + (size_t)(m0 + rs) * 2048 + cs;
  const _Float16* Bg = BT + (size_t)(n0 + rs) * 2048 + cs;
  _Float16* lAw = lA + w * 512;
  _Float16* lBw = lB + w * 512;
  f32x4 acc[4][4] = {};
  for (int k0 = 0; k0 < 2048; k0 += 64) {
#pragma unroll
    for (int i = 0; i < 4; ++i) {
      gl_lds16(Ag + k0 + (size_t)i * 32 * 2048, lAw + i * 2048);
      gl_lds16(Bg + k0 + (size_t)i * 32 * 2048, lBw + i * 2048);
    }
    __syncthreads();
#pragma unroll
    for (int ks = 0; ks < 2; ++ks) {
      const int ko = ks * 32 + 8 * lg;
      fp16x8 af[4], bf[4];
#pragma unroll
      for (int mi = 0; mi < 4; ++mi)
        af[mi] = *(const fp16x8*)&lA[(wm + mi * 16 + l15) * 64 + ko];
#pragma unroll
      for (int ni = 0; ni < 4; ++ni)
        bf[ni] = *(const fp16x8*)&lB[(wn + ni * 16 + l15) * 64 + ko];
#pragma unroll
      for (int mi = 0; mi < 4; ++mi)
#pragma unroll
        for (int ni = 0; ni < 4; ++ni)
          acc[mi][ni] = __builtin_amdgcn_mfma_f32_16x16x32_f16(af[mi], bf[ni], acc[mi][ni], 0, 0, 0);
    }
    __syncthreads();
  }
#pragma unroll
  for (int mi = 0; mi < 4; ++mi)
#pragma unroll
    for (int ni = 0; ni < 4; ++ni) {
      size_t row = m0 + wm + 16 * mi + 4 * lg;
      size_t col = n0 + wn + 16 * ni + l15;
#pragma unroll
      for (int i = 0; i < 4; ++i)
        C[(row + i) * (size_t)N + col] = (OUT)acc[mi][ni][i];
    }
}

// ---------------- RoPE: in fp16 (B,S,H,HD) -> out fp16 (B,H,S,HD) ----------------
__global__ __launch_bounds__(256) void k_rope(const _Float16* __restrict__ in,
                                              const float* __restrict__ cosT,
                                              const float* __restrict__ sinT,
                                              _Float16* __restrict__ out) {
  int idx = blockIdx.x * 256 + threadIdx.x;
  if (idx >= B_ * S_ * H_ * 64) return;
  int dp = idx & 63;
  int hh = (idx >> 6) & (H_ - 1);
  int s = (idx >> 10) & (S_ - 1);
  int b = idx >> 21;
  const _Float16* ip = in + (((size_t)b * S_ + s) * H_ + hh) * HD_ + 2 * dp;
  fp16x2 ab = *(const fp16x2*)ip;
  float a = (float)ab[0], bb = (float)ab[1];
  float c = cosT[s * 64 + dp], sn = sinT[s * 64 + dp];
  fp16x2 o = {(_Float16)(a * c - bb * sn), (_Float16)(a * sn + bb * c)};
  *(fp16x2*)(out + (((size_t)b * H_ + hh) * S_ + s) * HD_ + 2 * dp) = o;
}

// ---------------- V -> blocked layout: Vb[b][h][kb][128 d][16 k] ----------------
__global__ __launch_bounds__(256) void k_trvb(const _Float16* __restrict__ in,
                                              _Float16* __restrict__ out) {
  __shared__ _Float16 tile[16][136];
  const int kb = blockIdx.x, hh = blockIdx.y, b = blockIdx.z;
  const int t = threadIdx.x;
  const int kk = t >> 4, c8 = (t & 15) * 8;
  const _Float16* ip = in + (((size_t)b * S_ + kb * 16 + kk) * H_ + hh) * HD_ + c8;
  *(fp16x8*)&tile[kk][c8] = *(const fp16x8*)ip;
  __syncthreads();
  const int d = t >> 1, k8 = (t & 1) * 8;
  fp16x8 v;
#pragma unroll
  for (int j = 0; j < 8; ++j) v[j] = tile[k8 + j][d];
  *(fp16x8*)(out + ((((size_t)b * H_ + hh) * 128 + kb) * 128 + d) * 16 + k8) = v;
}

// ---------------- block-sparse flash attention, paired q-groups ----------------
// WG p handles q-groups qgA=31-p then qgB=p (flat chunk list, prefetch spans the
// boundary). Wave w owns qb=4*qg+w. K/V staged via global_load_lds, double-buffered.
__global__ __launch_bounds__(256) void k_attn(const _Float16* __restrict__ Q,
                                              const _Float16* __restrict__ K,
                                              const _Float16* __restrict__ Vb,
                                              _Float16* __restrict__ Oa) {
  __shared__ __align__(16) _Float16 sK[2][2][2048];  // [buf][slot][16k x 128d swizzled]
  __shared__ __align__(16) _Float16 sV[2][2][2048];  // [buf][slot][128d x 16k]
  const int p = blockIdx.x;
  const int qgA = 31 - p, qgB = p;
  const int hh = blockIdx.y, b = blockIdx.z;
  const int t = threadIdx.x;
  const int w = t >> 6, lane = t & 63;
  const int l15 = lane & 15, lg = lane >> 4, g4 = lg * 4;
  const size_t bh = (size_t)b * H_ + hh;
  const float scale = 0.08838834764831845f;  // 1/sqrt(128)

  const int qbA = 4 * qgA + w, qbB = 4 * qgB + w;
  const int LA = qgA + 4, LB = qgB + 4;
  const int nchA = (LA + 1) >> 1, nchB = (LB + 1) >> 1;
  const int total = nchA + nchB;

  // Q fragments for both groups (16x16x32 B-operand: 8 contiguous d per lane)
  const _Float16* QpA = Q + (bh * S_ + (size_t)qbA * 16 + l15) * HD_ + lg * 8;
  const _Float16* QpB = Q + (bh * S_ + (size_t)qbB * 16 + l15) * HD_ + lg * 8;
  fp16x8 qfA[4], qfB[4];
#pragma unroll
  for (int dd = 0; dd < 4; ++dd) {
    qfA[dd] = *(const fp16x8*)(QpA + dd * 32);
    qfB[dd] = *(const fp16x8*)(QpB + dd * 32);
  }
  f32x4 o[8] = {};
  float mrun = -3.0e38f, lsum = 0.f;

  // staging source coords (K pre-swizzled so LDS-linear dest ^ read-swizzle match)
  const int sr = t >> 4, sc = t & 15;
  const int ksrc_off = sr * 128 + (sc ^ (sr & 7)) * 8;  // halfs
  const _Float16* Kb_g = K + bh * S_ * HD_;
  const _Float16* Vb_g = Vb + bh * (size_t)(128 * 2048);

  auto kbof = [&](int qg, int idx) { return idx < qg ? 4 * idx + 3 : 3 * qg + idx; };
  auto chunk_kbs = [&](int ci, int& kb0, int& kb1) {
    int qg, cil;
    if (ci < nchA) { qg = qgA; cil = ci; } else { qg = qgB; cil = ci - nchA; }
    const int L = qg + 4;
    const int i0 = 2 * cil, i1 = i0 + 1;
    kb0 = kbof(qg, i0);
    kb1 = (i1 < L) ? kbof(qg, i1) : kb0;
  };
  auto stage = [&](int buf, int ci) {
    int kb0, kb1;
    chunk_kbs(ci, kb0, kb1);
    gl_lds16(Kb_g + (size_t)kb0 * 2048 + ksrc_off, &sK[buf][0][w * 512]);
    gl_lds16(Kb_g + (size_t)kb1 * 2048 + ksrc_off, &sK[buf][1][w * 512]);
    gl_lds16(Vb_g + (size_t)kb0 * 2048 + t * 8, &sV[buf][0][w * 512]);
    gl_lds16(Vb_g + (size_t)kb1 * 2048 + t * 8, &sV[buf][1][w * 512]);
  };
  auto flush = [&](int qb) {
    const float inv = 1.f / lsum;
    f32x4 li;
#pragma unroll
    for (int i = 0; i < 4; ++i) li[i] = __shfl(inv, g4 + i);
    _Float16* Op = Oa + ((size_t)b * S_ + (size_t)qb * 16 + g4) * D_ + (size_t)hh * HD_ + l15;
#pragma unroll
    for (int ni = 0; ni < 8; ++ni)
#pragma unroll
      for (int i = 0; i < 4; ++i)
        Op[(size_t)i * D_ + 16 * ni] = (_Float16)(o[ni][i] * li[i]);
  };

  stage(0, 0);

  for (int ci = 0; ci < total; ++ci) {
    const int cur = ci & 1;
    if (ci == nchA) {  // group A complete: write it out, reset state for B
      flush(qbA);
#pragma unroll
      for (int ni = 0; ni < 8; ++ni) o[ni] = f32x4{0.f, 0.f, 0.f, 0.f};
      mrun = -3.0e38f;
      lsum = 0.f;
    }
    if (ci + 1 < total) {
      stage(cur ^ 1, ci + 1);
      asm volatile("s_waitcnt vmcnt(4)" ::: "memory");  // cur chunk arrived, next in flight
    } else {
      asm volatile("s_waitcnt vmcnt(0)" ::: "memory");
    }
    __builtin_amdgcn_s_barrier();

    const bool inA = ci < nchA;
    const int qg = inA ? qgA : qgB;
    const int qb = inA ? qbA : qbB;
    const int cil = inA ? ci : ci - nchA;
    const int L = qg + 4;
    int kb0, kb1;
    chunk_kbs(ci, kb0, kb1);
    const bool v0 = kb0 <= qb;
    const bool v1 = (2 * cil + 1 < L) && (kb1 <= qb);
    f32x4 st[2];
    const float in0 = v0 ? 0.f : -1.0e30f, in1 = v1 ? 0.f : -1.0e30f;
    st[0] = f32x4{in0, in0, in0, in0};
    st[1] = f32x4{in1, in1, in1, in1};

    // QK^T via 16x16x32: A=K (16 keys x 32 d), B=Q (16 qrows x 32 d)
    const char* kl = (const char*)&sK[cur][0][0];
    const int krow = l15 * 256;
#pragma unroll
    for (int dd = 0; dd < 4; ++dd) {
      const int co = ((dd * 4 + lg) ^ (l15 & 7)) * 16;
      fp16x8 k0 = *(const fp16x8*)(kl + krow + co);
      fp16x8 k1 = *(const fp16x8*)(kl + 4096 + krow + co);
      const fp16x8 qf = inA ? qfA[dd] : qfB[dd];
      st[0] = __builtin_amdgcn_mfma_f32_16x16x32_f16(k0, qf, st[0], 0, 0, 0);
      st[1] = __builtin_amdgcn_mfma_f32_16x16x32_f16(k1, qf, st[1], 0, 0, 0);
    }
    // softmax over the 32 keys
    float bm = -3.0e38f;
#pragma unroll
    for (int j = 0; j < 2; ++j)
#pragma unroll
      for (int i = 0; i < 4; ++i) {
        st[j][i] *= scale;
        bm = fmaxf(bm, st[j][i]);
      }
    bm = fmaxf(bm, __shfl_xor(bm, 16));
    bm = fmaxf(bm, __shfl_xor(bm, 32));
    const float mnew = fmaxf(mrun, bm);
    const float corr = __expf(mrun - mnew);
    float pr[2][4];
    float ps = 0.f;
#pragma unroll
    for (int j = 0; j < 2; ++j)
#pragma unroll
      for (int i = 0; i < 4; ++i) {
        pr[j][i] = __expf(st[j][i] - mnew);
        ps += pr[j][i];
      }
    ps += __shfl_xor(ps, 16);
    ps += __shfl_xor(ps, 32);
    lsum = lsum * corr + ps;
    mrun = mnew;
    f32x4 c4;
#pragma unroll
    for (int i = 0; i < 4; ++i) c4[i] = __shfl(corr, g4 + i);
#pragma unroll
    for (int ni = 0; ni < 8; ++ni) {
      o[ni][0] *= c4[0]; o[ni][1] *= c4[1]; o[ni][2] *= c4[2]; o[ni][3] *= c4[3];
    }
    fp16x4 ph0 = {(_Float16)pr[0][0], (_Float16)pr[0][1], (_Float16)pr[0][2], (_Float16)pr[0][3]};
    fp16x4 ph1 = {(_Float16)pr[1][0], (_Float16)pr[1][1], (_Float16)pr[1][2], (_Float16)pr[1][3]};
    const char* vl = (const char*)&sV[cur][0][0];
#pragma unroll
    for (int ni = 0; ni < 8; ++ni) {
      const int vo = (16 * ni + l15) * 32 + g4 * 2;
      fp16x4 vv0 = *(const fp16x4*)(vl + vo);
      fp16x4 vv1 = *(const fp16x4*)(vl + 4096 + vo);
      o[ni] = __builtin_amdgcn_mfma_f32_16x16x16f16(ph0, vv0, o[ni], 0, 0, 0);
      o[ni] = __builtin_amdgcn_mfma_f32_16x16x16f16(ph1, vv1, o[ni], 0, 0, 0);
    }
    __builtin_amdgcn_s_barrier();  // all waves done reading buf before it's re-staged
  }

  flush(qbB);
}

extern "C" void kernel_launch(void* const* d_in, const int* in_sizes, int n_in,
                              void* d_out, int out_size, void* d_ws, size_t ws_size,
                              hipStream_t stream) {
  const float* x = (const float*)d_in[0];
  const float* cosT = (const float*)d_in[1];
  const float* sinT = (const float*)d_in[2];
  const float* wq = (const float*)d_in[3];
  const float* wk = (const float*)d_in[4];
  const float* wv = (const float*)d_in[5];
  const float* wo = (const float*)d_in[6];
  float* out = (float*)d_out;
  char* ws = (char*)d_ws;

  _Float16* x16 = (_Float16*)(ws);                    // 16MB, reused as attn out
  _Float16* wtq = (_Float16*)(ws + (16ull << 20));    // 8MB each
  _Float16* wtk = (_Float16*)(ws + (24ull << 20));
  _Float16* wtv = (_Float16*)(ws + (32ull << 20));
  _Float16* wto = (_Float16*)(ws + (40ull << 20));
  _Float16* Q16 = (_Float16*)(ws + (48ull << 20));    // 16MB
  _Float16* K16 = (_Float16*)(ws + (64ull << 20));    // 16MB
  _Float16* Vb16 = (_Float16*)(ws + (80ull << 20));   // 16MB (blocked V)
  _Float16* tmp16 = (_Float16*)(ws + (96ull << 20));  // 16MB -> 112MB total

  k_cast<<<8192, 256, 0, stream>>>(x, x16, (B_ * S_ * D_) / 4);
  k_trw4<<<dim3(32, 32, 4), 256, 0, stream>>>(wq, wk, wv, wo, wtq, wtk, wtv, wto);

  dim3 gg(D_ / 128, (B_ * S_) / 128);  // (16, 32)
  k_gemm_bt<_Float16><<<gg, 256, 0, stream>>>(x16, wtq, tmp16, D_);
  k_rope<<<16384, 256, 0, stream>>>(tmp16, cosT, sinT, Q16);
  k_gemm_bt<_Float16><<<gg, 256, 0, stream>>>(x16, wtk, tmp16, D_);
  k_rope<<<16384, 256, 0, stream>>>(tmp16, cosT, sinT, K16);
  k_gemm_bt<_Float16><<<gg, 256, 0, stream>>>(x16, wtv, tmp16, D_);
  k_trvb<<<dim3(128, 16, 2), 256, 0, stream>>>(tmp16, Vb16);

  _Float16* attn16 = x16;  // x16 no longer needed
  k_attn<<<dim3(16, H_, B_), 256, 0, stream>>>(Q16, K16, Vb16, attn16);

  k_gemm_bt<float><<<gg, 256, 0, stream>>>(attn16, wto, out, D_);
}

// Round 6
// 238.869 us; speedup vs baseline: 1.8680x; 1.2480x over previous
//
#include <hip/hip_runtime.h>

#define B_ 2
#define S_ 2048
#define D_ 2048
#define H_ 16
#define HD_ 128

typedef _Float16 fp16x2 __attribute__((ext_vector_type(2)));
typedef _Float16 fp16x4 __attribute__((ext_vector_type(4)));
typedef _Float16 fp16x8 __attribute__((ext_vector_type(8)));
typedef float f32x4 __attribute__((ext_vector_type(4)));

__device__ __forceinline__ void gl_lds16(const _Float16* g, _Float16* l) {
  __builtin_amdgcn_global_load_lds((const __attribute__((address_space(1))) void*)g,
                                   (__attribute__((address_space(3))) void*)l, 16, 0, 0);
}

// ---------------- cast x fp32 -> fp16 ----------------
__global__ __launch_bounds__(256) void k_cast(const float* __restrict__ in,
                                              _Float16* __restrict__ out, int n4) {
  int i = blockIdx.x * 256 + threadIdx.x;
  if (i >= n4) return;
  f32x4 v = ((const f32x4*)in)[i];
  fp16x4 h = {(_Float16)v[0], (_Float16)v[1], (_Float16)v[2], (_Float16)v[3]};
  ((fp16x4*)out)[i] = h;
}

// ---------------- transpose+cast 4x W[2048][2048] fp32 -> WT[n][k] fp16 ----------------
__global__ __launch_bounds__(256) void k_trw4(const float* __restrict__ w0,
                                              const float* __restrict__ w1,
                                              const float* __restrict__ w2,
                                              const float* __restrict__ w3,
                                              _Float16* __restrict__ o0,
                                              _Float16* __restrict__ o1,
                                              _Float16* __restrict__ o2,
                                              _Float16* __restrict__ o3) {
  __shared__ float tile[64][65];
  const float* w = (blockIdx.z == 0) ? w0 : (blockIdx.z == 1) ? w1 : (blockIdx.z == 2) ? w2 : w3;
  _Float16* wt = (blockIdx.z == 0) ? o0 : (blockIdx.z == 1) ? o1 : (blockIdx.z == 2) ? o2 : o3;
  int k0 = blockIdx.y * 64, n0 = blockIdx.x * 64;
  int t = threadIdx.x;
  int r = t >> 2, c0 = (t & 3) * 16;
  const float* ip = w + (size_t)(k0 + r) * D_ + n0 + c0;
#pragma unroll
  for (int j = 0; j < 16; j += 4) {
    f32x4 v = *(const f32x4*)(ip + j);
    tile[r][c0 + j] = v[0]; tile[r][c0 + j + 1] = v[1];
    tile[r][c0 + j + 2] = v[2]; tile[r][c0 + j + 3] = v[3];
  }
  __syncthreads();
  _Float16* op = wt + (size_t)(n0 + r) * D_ + k0 + c0;
#pragma unroll
  for (int j = 0; j < 16; j += 8) {
    fp16x8 v;
#pragma unroll
    for (int q = 0; q < 8; ++q) v[q] = (_Float16)tile[c0 + j + q][r];
    *(fp16x8*)(op + j) = v;
  }
}

// ---------------- fused QKV GEMM + RoPE + layout epilogue ----------------
// C[4096][6144] = A16[4096][2048] * (BTqkv[6144][2048])^T, never materialized:
//   n in [0,2048)    -> rope -> Qo (B,H,S,HD)
//   n in [2048,4096) -> rope -> Ko (B,H,S,HD)
//   n in [4096,6144) -> Vo blocked [b][h][kb][128 d][16 k]
__global__ __launch_bounds__(256, 4) void k_gemm_qkv(const _Float16* __restrict__ A,
                                                     const _Float16* __restrict__ BT,
                                                     const float* __restrict__ cosT,
                                                     const float* __restrict__ sinT,
                                                     _Float16* __restrict__ Qo,
                                                     _Float16* __restrict__ Ko,
                                                     _Float16* __restrict__ Vo) {
  __shared__ __align__(16) _Float16 lA[128 * 64];
  __shared__ __align__(16) _Float16 lB[128 * 64];
  const int t = threadIdx.x;
  // XCD mapping: grid (48,32) -> 1536 WGs; XCD x owns n-cols [x*768,(x+1)*768)
  const int fid = blockIdx.y * 48 + blockIdx.x;
  const int xcd = fid & 7, j = fid >> 3;  // j in [0,192)
  const int m0 = (j / 6) * 128;
  const int n0 = (xcd * 6 + j % 6) * 128;
  const int lane = t & 63, w = t >> 6;
  const int l15 = lane & 15, lg = lane >> 4;
  const int wm = (w >> 1) * 64, wn = (w & 1) * 64;
  const int rs = t >> 3, cs = (t & 7) * 8;
  const _Float16* Ag = A + (size_t)(m0 + rs) * 2048 + cs;
  const _Float16* Bg = BT + (size_t)(n0 + rs) * 2048 + cs;
  _Float16* lAw = lA + w * 512;
  _Float16* lBw = lB + w * 512;
  f32x4 acc[4][4] = {};
  for (int k0 = 0; k0 < 2048; k0 += 64) {
#pragma unroll
    for (int i = 0; i < 4; ++i) {
      gl_lds16(Ag + k0 + (size_t)i * 32 * 2048, lAw + i * 2048);
      gl_lds16(Bg + k0 + (size_t)i * 32 * 2048, lBw + i * 2048);
    }
    __syncthreads();
#pragma unroll
    for (int ks = 0; ks < 2; ++ks) {
      const int ko = ks * 32 + 8 * lg;
      fp16x8 af[4], bf[4];
#pragma unroll
      for (int mi = 0; mi < 4; ++mi)
        af[mi] = *(const fp16x8*)&lA[(wm + mi * 16 + l15) * 64 + ko];
#pragma unroll
      for (int ni = 0; ni < 4; ++ni)
        bf[ni] = *(const fp16x8*)&lB[(wn + ni * 16 + l15) * 64 + ko];
#pragma unroll
      for (int mi = 0; mi < 4; ++mi)
#pragma unroll
        for (int ni = 0; ni < 4; ++ni)
          acc[mi][ni] = __builtin_amdgcn_mfma_f32_16x16x32_f16(af[mi], bf[ni], acc[mi][ni], 0, 0, 0);
    }
    __syncthreads();
  }

  const int region = n0 >> 11;  // 0=Q, 1=K, 2=V (128-tile never crosses a region)
  if (region < 2) {
    _Float16* Out = (region == 0) ? Qo : Ko;
#pragma unroll
    for (int mi = 0; mi < 4; ++mi)
#pragma unroll
      for (int ni = 0; ni < 4; ++ni) {
        const int col = n0 + wn + 16 * ni + l15;
        const int d = col & 127;
        const int h = (col >> 7) & 15;
        const int dp = d >> 1;
        const bool odd = d & 1;
#pragma unroll
        for (int i = 0; i < 4; ++i) {
          const int row = m0 + wm + 16 * mi + 4 * lg + i;
          const int b = row >> 11, sl = row & 2047;
          const float self = acc[mi][ni][i];
          const float partner = __shfl_xor(self, 1);
          const float c = cosT[sl * 64 + dp], sn = sinT[sl * 64 + dp];
          const float val = odd ? (partner * sn + self * c) : (self * c - partner * sn);
          Out[(((size_t)b * H_ + h) * S_ + sl) * HD_ + d] = (_Float16)val;
        }
      }
  } else {
#pragma unroll
    for (int mi = 0; mi < 4; ++mi)
#pragma unroll
      for (int ni = 0; ni < 4; ++ni) {
        const int col = n0 + wn + 16 * ni + l15;
        const int d = col & 127;
        const int h = (col >> 7) & 15;
        const int row0 = m0 + wm + 16 * mi + 4 * lg;
        const int b = row0 >> 11, sl0 = row0 & 2047;
        const int kb = sl0 >> 4, kin = sl0 & 15;
        fp16x4 v4;
#pragma unroll
        for (int i = 0; i < 4; ++i) v4[i] = (_Float16)acc[mi][ni][i];
        *(fp16x4*)(Vo + ((((size_t)b * H_ + h) * 128 + kb) * 128 + d) * 16 + kin) = v4;
      }
  }
}

// ---------------- GEMM (m97 structure + XCD swizzle): C = A16 * BT16^T ----------------
template <typename OUT>
__global__ __launch_bounds__(256) void k_gemm_bt(const _Float16* __restrict__ A,
                                                 const _Float16* __restrict__ BT,
                                                 OUT* __restrict__ C, int N) {
  __shared__ __align__(16) _Float16 lA[128 * 64];
  __shared__ __align__(16) _Float16 lB[128 * 64];
  const int t = threadIdx.x;
  // grid (16,32) = 512 WGs; XCD x owns n-cols [x*256,(x+1)*256)
  const int fid = blockIdx.y * 16 + blockIdx.x;
  const int xcd = fid & 7, j = fid >> 3;  // j in [0,64)
  const int m0 = (j >> 1) * 128;
  const int n0 = (xcd * 2 + (j & 1)) * 128;
  const int lane = t & 63, w = t >> 6;
  const int l15 = lane & 15, lg = lane >> 4;
  const int wm = (w >> 1) * 64, wn = (w & 1) * 64;
  const int rs = t >> 3, cs = (t & 7) * 8;
  const _Float16* Ag = A + (size_t)(m0 + rs) * 2048 + cs;
  const _Float16* Bg = BT + (size_t)(n0 + rs) * 2048 + cs;
  _Float16* lAw = lA + w * 512;
  _Float16* lBw = lB + w * 512;
  f32x4 acc[4][4] = {};
  for (int k0 = 0; k0 < 2048; k0 += 64) {
#pragma unroll
    for (int i = 0; i < 4; ++i) {
      gl_lds16(Ag + k0 + (size_t)i * 32 * 2048, lAw + i * 2048);
      gl_lds16(Bg + k0 + (size_t)i * 32 * 2048, lBw + i * 2048);
    }
    __syncthreads();
#pragma unroll
    for (int ks = 0; ks < 2; ++ks) {
      const int ko = ks * 32 + 8 * lg;
      fp16x8 af[4], bf[4];
#pragma unroll
      for (int mi = 0; mi < 4; ++mi)
        af[mi] = *(const fp16x8*)&lA[(wm + mi * 16 + l15) * 64 + ko];
#pragma unroll
      for (int ni = 0; ni < 4; ++ni)
        bf[ni] = *(const fp16x8*)&lB[(wn + ni * 16 + l15) * 64 + ko];
#pragma unroll
      for (int mi = 0; mi < 4; ++mi)
#pragma unroll
        for (int ni = 0; ni < 4; ++ni)
          acc[mi][ni] = __builtin_amdgcn_mfma_f32_16x16x32_f16(af[mi], bf[ni], acc[mi][ni], 0, 0, 0);
    }
    __syncthreads();
  }
#pragma unroll
  for (int mi = 0; mi < 4; ++mi)
#pragma unroll
    for (int ni = 0; ni < 4; ++ni) {
      size_t row = m0 + wm + 16 * mi + 4 * lg;
      size_t col = n0 + wn + 16 * ni + l15;
#pragma unroll
      for (int i = 0; i < 4; ++i)
        C[(row + i) * (size_t)N + col] = (OUT)acc[mi][ni][i];
    }
}

// ---------------- block-sparse flash attention, paired q-groups ----------------
// WG p handles q-groups qgA=31-p then qgB=p (flat chunk list, prefetch spans the
// boundary). Wave w owns qb=4*qg+w. K/V staged via global_load_lds, double-buffered.
__global__ __launch_bounds__(256) void k_attn(const _Float16* __restrict__ Q,
                                              const _Float16* __restrict__ K,
                                              const _Float16* __restrict__ Vb,
                                              _Float16* __restrict__ Oa) {
  __shared__ __align__(16) _Float16 sK[2][2][2048];  // [buf][slot][16k x 128d swizzled]
  __shared__ __align__(16) _Float16 sV[2][2][2048];  // [buf][slot][128d x 16k]
  const int p = blockIdx.x;
  const int qgA = 31 - p, qgB = p;
  const int hh = blockIdx.y, b = blockIdx.z;
  const int t = threadIdx.x;
  const int w = t >> 6, lane = t & 63;
  const int l15 = lane & 15, lg = lane >> 4, g4 = lg * 4;
  const size_t bh = (size_t)b * H_ + hh;
  const float scale = 0.08838834764831845f;  // 1/sqrt(128)

  const int qbA = 4 * qgA + w, qbB = 4 * qgB + w;
  const int LA = qgA + 4, LB = qgB + 4;
  const int nchA = (LA + 1) >> 1, nchB = (LB + 1) >> 1;
  const int total = nchA + nchB;

  // Q fragments for both groups (16x16x32 B-operand: 8 contiguous d per lane)
  const _Float16* QpA = Q + (bh * S_ + (size_t)qbA * 16 + l15) * HD_ + lg * 8;
  const _Float16* QpB = Q + (bh * S_ + (size_t)qbB * 16 + l15) * HD_ + lg * 8;
  fp16x8 qfA[4], qfB[4];
#pragma unroll
  for (int dd = 0; dd < 4; ++dd) {
    qfA[dd] = *(const fp16x8*)(QpA + dd * 32);
    qfB[dd] = *(const fp16x8*)(QpB + dd * 32);
  }
  f32x4 o[8] = {};
  float mrun = -3.0e38f, lsum = 0.f;

  // staging source coords (K pre-swizzled so LDS-linear dest ^ read-swizzle match)
  const int sr = t >> 4, sc = t & 15;
  const int ksrc_off = sr * 128 + (sc ^ (sr & 7)) * 8;  // halfs
  const _Float16* Kb_g = K + bh * S_ * HD_;
  const _Float16* Vb_g = Vb + bh * (size_t)(128 * 2048);

  auto kbof = [&](int qg, int idx) { return idx < qg ? 4 * idx + 3 : 3 * qg + idx; };
  auto chunk_kbs = [&](int ci, int& kb0, int& kb1) {
    int qg, cil;
    if (ci < nchA) { qg = qgA; cil = ci; } else { qg = qgB; cil = ci - nchA; }
    const int L = qg + 4;
    const int i0 = 2 * cil, i1 = i0 + 1;
    kb0 = kbof(qg, i0);
    kb1 = (i1 < L) ? kbof(qg, i1) : kb0;
  };
  auto stage = [&](int buf, int ci) {
    int kb0, kb1;
    chunk_kbs(ci, kb0, kb1);
    gl_lds16(Kb_g + (size_t)kb0 * 2048 + ksrc_off, &sK[buf][0][w * 512]);
    gl_lds16(Kb_g + (size_t)kb1 * 2048 + ksrc_off, &sK[buf][1][w * 512]);
    gl_lds16(Vb_g + (size_t)kb0 * 2048 + t * 8, &sV[buf][0][w * 512]);
    gl_lds16(Vb_g + (size_t)kb1 * 2048 + t * 8, &sV[buf][1][w * 512]);
  };
  auto flush = [&](int qb) {
    const float inv = 1.f / lsum;
    f32x4 li;
#pragma unroll
    for (int i = 0; i < 4; ++i) li[i] = __shfl(inv, g4 + i);
    _Float16* Op = Oa + ((size_t)b * S_ + (size_t)qb * 16 + g4) * D_ + (size_t)hh * HD_ + l15;
#pragma unroll
    for (int ni = 0; ni < 8; ++ni)
#pragma unroll
      for (int i = 0; i < 4; ++i)
        Op[(size_t)i * D_ + 16 * ni] = (_Float16)(o[ni][i] * li[i]);
  };

  stage(0, 0);

  for (int ci = 0; ci < total; ++ci) {
    const int cur = ci & 1;
    if (ci == nchA) {  // group A complete: write it out, reset state for B
      flush(qbA);
#pragma unroll
      for (int ni = 0; ni < 8; ++ni) o[ni] = f32x4{0.f, 0.f, 0.f, 0.f};
      mrun = -3.0e38f;
      lsum = 0.f;
    }
    if (ci + 1 < total) {
      stage(cur ^ 1, ci + 1);
      asm volatile("s_waitcnt vmcnt(4)" ::: "memory");  // cur chunk arrived, next in flight
    } else {
      asm volatile("s_waitcnt vmcnt(0)" ::: "memory");
    }
    __builtin_amdgcn_s_barrier();

    const bool inA = ci < nchA;
    const int qg = inA ? qgA : qgB;
    const int qb = inA ? qbA : qbB;
    const int cil = inA ? ci : ci - nchA;
    const int L = qg + 4;
    int kb0, kb1;
    chunk_kbs(ci, kb0, kb1);
    const bool v0 = kb0 <= qb;
    const bool v1 = (2 * cil + 1 < L) && (kb1 <= qb);
    f32x4 st[2];
    const float in0 = v0 ? 0.f : -1.0e30f, in1 = v1 ? 0.f : -1.0e30f;
    st[0] = f32x4{in0, in0, in0, in0};
    st[1] = f32x4{in1, in1, in1, in1};

    // QK^T via 16x16x32: A=K (16 keys x 32 d), B=Q (16 qrows x 32 d)
    const char* kl = (const char*)&sK[cur][0][0];
    const int krow = l15 * 256;
#pragma unroll
    for (int dd = 0; dd < 4; ++dd) {
      const int co = ((dd * 4 + lg) ^ (l15 & 7)) * 16;
      fp16x8 k0 = *(const fp16x8*)(kl + krow + co);
      fp16x8 k1 = *(const fp16x8*)(kl + 4096 + krow + co);
      const fp16x8 qf = inA ? qfA[dd] : qfB[dd];
      st[0] = __builtin_amdgcn_mfma_f32_16x16x32_f16(k0, qf, st[0], 0, 0, 0);
      st[1] = __builtin_amdgcn_mfma_f32_16x16x32_f16(k1, qf, st[1], 0, 0, 0);
    }
    // softmax over the 32 keys
    float bm = -3.0e38f;
#pragma unroll
    for (int j = 0; j < 2; ++j)
#pragma unroll
      for (int i = 0; i < 4; ++i) {
        st[j][i] *= scale;
        bm = fmaxf(bm, st[j][i]);
      }
    bm = fmaxf(bm, __shfl_xor(bm, 16));
    bm = fmaxf(bm, __shfl_xor(bm, 32));
    const float mnew = fmaxf(mrun, bm);
    const float corr = __expf(mrun - mnew);
    float pr[2][4];
    float ps = 0.f;
#pragma unroll
    for (int j = 0; j < 2; ++j)
#pragma unroll
      for (int i = 0; i < 4; ++i) {
        pr[j][i] = __expf(st[j][i] - mnew);
        ps += pr[j][i];
      }
    ps += __shfl_xor(ps, 16);
    ps += __shfl_xor(ps, 32);
    lsum = lsum * corr + ps;
    mrun = mnew;
    f32x4 c4;
#pragma unroll
    for (int i = 0; i < 4; ++i) c4[i] = __shfl(corr, g4 + i);
#pragma unroll
    for (int ni = 0; ni < 8; ++ni) {
      o[ni][0] *= c4[0]; o[ni][1] *= c4[1]; o[ni][2] *= c4[2]; o[ni][3] *= c4[3];
    }
    fp16x4 ph0 = {(_Float16)pr[0][0], (_Float16)pr[0][1], (_Float16)pr[0][2], (_Float16)pr[0][3]};
    fp16x4 ph1 = {(_Float16)pr[1][0], (_Float16)pr[1][1], (_Float16)pr[1][2], (_Float16)pr[1][3]};
    const char* vl = (const char*)&sV[cur][0][0];
#pragma unroll
    for (int ni = 0; ni < 8; ++ni) {
      const int vo = (16 * ni + l15) * 32 + g4 * 2;
      fp16x4 vv0 = *(const fp16x4*)(vl + vo);
      fp16x4 vv1 = *(const fp16x4*)(vl + 4096 + vo);
      o[ni] = __builtin_amdgcn_mfma_f32_16x16x16f16(ph0, vv0, o[ni], 0, 0, 0);
      o[ni] = __builtin_amdgcn_mfma_f32_16x16x16f16(ph1, vv1, o[ni], 0, 0, 0);
    }
    __builtin_amdgcn_s_barrier();  // all waves done reading buf before it's re-staged
  }

  flush(qbB);
}

extern "C" void kernel_launch(void* const* d_in, const int* in_sizes, int n_in,
                              void* d_out, int out_size, void* d_ws, size_t ws_size,
                              hipStream_t stream) {
  const float* x = (const float*)d_in[0];
  const float* cosT = (const float*)d_in[1];
  const float* sinT = (const float*)d_in[2];
  const float* wq = (const float*)d_in[3];
  const float* wk = (const float*)d_in[4];
  const float* wv = (const float*)d_in[5];
  const float* wo = (const float*)d_in[6];
  float* out = (float*)d_out;
  char* ws = (char*)d_ws;

  _Float16* x16 = (_Float16*)(ws);                    // 16MB, reused as attn out
  _Float16* wtq = (_Float16*)(ws + (16ull << 20));    // 8MB each; wtq/wtk/wtv contiguous = BT[6144][2048]
  _Float16* wtk = (_Float16*)(ws + (24ull << 20));
  _Float16* wtv = (_Float16*)(ws + (32ull << 20));
  _Float16* wto = (_Float16*)(ws + (40ull << 20));
  _Float16* Q16 = (_Float16*)(ws + (48ull << 20));    // 16MB
  _Float16* K16 = (_Float16*)(ws + (64ull << 20));    // 16MB
  _Float16* Vb16 = (_Float16*)(ws + (80ull << 20));   // 16MB (blocked V)

  k_cast<<<8192, 256, 0, stream>>>(x, x16, (B_ * S_ * D_) / 4);
  k_trw4<<<dim3(32, 32, 4), 256, 0, stream>>>(wq, wk, wv, wo, wtq, wtk, wtv, wto);

  k_gemm_qkv<<<dim3(48, 32), 256, 0, stream>>>(x16, wtq, cosT, sinT, Q16, K16, Vb16);

  _Float16* attn16 = x16;  // x16 no longer needed after QKV GEMM
  k_attn<<<dim3(16, H_, B_), 256, 0, stream>>>(Q16, K16, Vb16, attn16);

  dim3 gg(D_ / 128, (B_ * S_) / 128);  // (16, 32)
  k_gemm_bt<float><<<gg, 256, 0, stream>>>(attn16, wto, out, D_);
}